// Round 1
// baseline (421.097 us; speedup 1.0000x reference)
//
#include <hip/hip_runtime.h>

// MTFNet: N=8, C=8, H=W=256, L=11, SF=2, h=w=128
// Pipeline:
//  K1: E2[n][c'][p] = (blur(x,k) - y) stored via flat reinterpret (p*8+c' = flat(C,h,w))
//  K2: G[n][ki*11+kj][c] = (1/16384) * sum_p xp[n,c,ki+2pr,kj+2ps] * E2[n][c][p]
//  K3: per-n pronet (9 convs, residual blocks) on G_K = k - 0.1*gamma*G (flat), + normalize

__device__ __forceinline__ int refl(int m) {
    m = (m < 0) ? -m : m;
    return (m > 255) ? (510 - m) : m;
}

// ---------------- K1: blur + subtract y, store transposed E2 ----------------
// grid = 64 (n*c) * 16 (row blocks of 8) = 1024 blocks, 256 threads
// thread -> 1 row r, 4 consecutive ps outputs
__global__ __launch_bounds__(256) void blur_kernel(
        const float* __restrict__ x, const float* __restrict__ y,
        const float* __restrict__ kk, float* __restrict__ E2) {
    __shared__ float kl[121];
    int bid = blockIdx.x;
    int rowblk = bid & 15;
    int nc = bid >> 4;                 // n*8 + c
    int t = threadIdx.x;
    if (t < 121) kl[t] = kk[nc * 121 + t];
    __syncthreads();
    int r = rowblk * 8 + (t >> 5);     // output row 0..127
    int ps0 = (t & 31) * 4;            // output col base
    const float* xb = x + nc * 65536;
    float a0 = 0.f, a1 = 0.f, a2 = 0.f, a3 = 0.f;
    int cb = 2 * ps0 - 5;              // padded col base (pre-reflect)
    #pragma unroll
    for (int i = 0; i < 11; ++i) {
        int iy = refl(2 * r - 5 + i);
        const float* row = xb + iy * 256;
        float c[17];
        #pragma unroll
        for (int u = 0; u < 17; ++u) c[u] = row[refl(cb + u)];
        #pragma unroll
        for (int j = 0; j < 11; ++j) {
            float kv = kl[i * 11 + j];
            a0 = fmaf(c[j],     kv, a0);
            a1 = fmaf(c[j + 2], kv, a1);
            a2 = fmaf(c[j + 4], kv, a2);
            a3 = fmaf(c[j + 6], kv, a3);
        }
    }
    int n = nc >> 3;
    int o = nc * 16384 + r * 128 + ps0;          // flat [N][C][128][128]
    float4 yv = *reinterpret_cast<const float4*>(y + o);
    float e[4] = {a0 - yv.x, a1 - yv.y, a2 - yv.z, a3 - yv.w};
    // reinterpret flat-within-n index q as (p = q>>3, c' = q&7); store E2[n][c'][p]
    int qn = o - n * 131072;
    int p = qn >> 3;                   // same for all 4 (qn%8 in {0,4})
    int cbase = qn & 7;
    float* eb = E2 + n * 131072 + p;
    #pragma unroll
    for (int qq = 0; qq < 4; ++qq)
        eb[(cbase + qq) * 16384] = e[qq];
}

// ---------------- K2: G contraction ----------------
// grid = 64 (n*c) * 11 (ki) = 704 blocks, 256 threads
// thread: ps group of 4 (t&31), row subset pr = (t>>5) + 8*it, it=0..15
__global__ __launch_bounds__(256) void grad_kernel(
        const float* __restrict__ x, const float* __restrict__ E2,
        float* __restrict__ G) {
    int bid = blockIdx.x;
    int ki = bid % 11;
    int nc = bid / 11;
    int n = nc >> 3, c = nc & 7;
    const float* xb = x + nc * 65536;
    const float* Eb = E2 + n * 131072 + c * 16384;
    int t = threadIdx.x;
    int ps0 = (t & 31) * 4;
    int pr0 = t >> 5;
    int cb = 2 * ps0 - 5;
    float acc[11];
    #pragma unroll
    for (int j = 0; j < 11; ++j) acc[j] = 0.f;
    for (int it = 0; it < 16; ++it) {
        int pr = pr0 + (it << 3);
        int iy = refl(ki + 2 * pr - 5);
        const float* row = xb + iy * 256;
        float cbuf[17];
        #pragma unroll
        for (int u = 0; u < 17; ++u) cbuf[u] = row[refl(cb + u)];
        float4 ev = *reinterpret_cast<const float4*>(Eb + pr * 128 + ps0);
        #pragma unroll
        for (int j = 0; j < 11; ++j) {
            float v = acc[j];
            v = fmaf(cbuf[j],     ev.x, v);
            v = fmaf(cbuf[j + 2], ev.y, v);
            v = fmaf(cbuf[j + 4], ev.z, v);
            v = fmaf(cbuf[j + 6], ev.w, v);
            acc[j] = v;
        }
    }
    // block reduction: 4 waves
    __shared__ float part[4][11];
    int lane = t & 63, wid = t >> 6;
    #pragma unroll
    for (int j = 0; j < 11; ++j) {
        float v = acc[j];
        #pragma unroll
        for (int off = 32; off > 0; off >>= 1)
            v += __shfl_down(v, off, 64);
        if (lane == 0) part[wid][j] = v;
    }
    __syncthreads();
    if (t < 11) {
        float s = part[0][t] + part[1][t] + part[2][t] + part[3][t];
        G[n * 968 + (ki * 11 + t) * 8 + c] = s * (1.0f / 16384.0f);
    }
}

// ---------------- K3: pronet + normalize, one block per n ----------------
struct PArgs {
    const float* W[9];   // w1a,w1b,w2a,w2b,w3a,w3b,w4a,w4b,w5
    const float* B[9];
    const float* k;
    const float* gamma;
    const float* G;
    float* out;
};

__device__ void conv3x3_8(const float* __restrict__ in, const float* __restrict__ w,
                          const float* __restrict__ b, float* __restrict__ out,
                          bool relu_out) {
    for (int o = threadIdx.x; o < 968; o += 256) {
        int co = o / 121;
        int rem = o - co * 121;
        int yy = rem / 11;
        int xx = rem - yy * 11;
        float acc = b[co];
        const float* wc = w + co * 72;
        #pragma unroll
        for (int ci = 0; ci < 8; ++ci) {
            const float* ip = in + ci * 121;
            const float* wp = wc + ci * 9;
            #pragma unroll
            for (int dy = 0; dy < 3; ++dy) {
                int iy = yy + dy - 1;
                if (iy < 0 || iy > 10) continue;
                #pragma unroll
                for (int dx = 0; dx < 3; ++dx) {
                    int ix = xx + dx - 1;
                    if (ix < 0 || ix > 10) continue;
                    acc = fmaf(ip[iy * 11 + ix], wp[dy * 3 + dx], acc);
                }
            }
        }
        out[o] = relu_out ? fmaxf(acc, 0.f) : acc;
    }
}

__global__ __launch_bounds__(256) void pronet_kernel(PArgs pa) {
    __shared__ float g[968], cur[968], t1[968], t2[968];
    __shared__ float csum[8];
    int n = blockIdx.x;
    int t = threadIdx.x;
    float gm = pa.gamma[0] * 0.1f;
    for (int o = t; o < 968; o += 256) {
        // G_K flat reinterpretation: elementwise in flat order
        float v = pa.k[n * 968 + o] - gm * pa.G[n * 968 + o];
        g[o] = v;
        cur[o] = v;
    }
    __syncthreads();
    #pragma unroll
    for (int rb = 0; rb < 4; ++rb) {
        conv3x3_8(cur, pa.W[2 * rb], pa.B[2 * rb], t1, true);
        __syncthreads();
        conv3x3_8(t1, pa.W[2 * rb + 1], pa.B[2 * rb + 1], t2, false);
        __syncthreads();
        for (int o = t; o < 968; o += 256)
            cur[o] = fmaxf(cur[o] + 0.1f * t2[o], 0.f);
        __syncthreads();
    }
    conv3x3_8(cur, pa.W[8], pa.B[8], t2, false);
    __syncthreads();
    for (int o = t; o < 968; o += 256)
        t1[o] = fmaxf(g[o] + 0.1f * t2[o], 0.f);
    __syncthreads();
    if (t < 8) {
        float s = 0.f;
        for (int q = 0; q < 121; ++q) s += t1[t * 121 + q];
        csum[t] = s;
    }
    __syncthreads();
    for (int o = t; o < 968; o += 256)
        pa.out[n * 968 + o] = t1[o] / csum[o / 121];
}

extern "C" void kernel_launch(void* const* d_in, const int* in_sizes, int n_in,
                              void* d_out, int out_size, void* d_ws, size_t ws_size,
                              hipStream_t stream) {
    const float* x = (const float*)d_in[0];
    const float* y = (const float*)d_in[1];
    const float* k = (const float*)d_in[2];
    // d_in[3] = sf (int, constant 2) — unused
    const float* gamma = (const float*)d_in[4];

    float* E2 = (float*)d_ws;            // 8*131072 floats = 4 MB
    float* G  = E2 + 8 * 131072;         // 7744 floats

    blur_kernel<<<1024, 256, 0, stream>>>(x, y, k, E2);
    grad_kernel<<<704, 256, 0, stream>>>(x, E2, G);

    PArgs pa;
    for (int i = 0; i < 9; ++i) {
        pa.W[i] = (const float*)d_in[5 + 2 * i];
        pa.B[i] = (const float*)d_in[6 + 2 * i];
    }
    pa.k = k;
    pa.gamma = gamma;
    pa.G = G;
    pa.out = (float*)d_out;
    pronet_kernel<<<8, 256, 0, stream>>>(pa);
}

// Round 3
// 231.786 us; speedup vs baseline: 1.8167x; 1.8167x over previous
//
#include <hip/hip_runtime.h>

// MTFNet: N=8, C=8, H=W=256, L=11, SF=2, h=w=128
// Pipeline:
//  K1: E2[n][c'][p] = (blur(x,k) - y) stored via flat reinterpret (p*8+c' = flat(C,h,w))
//  K2: G[n][ki*11+kj][c] = (1/16384) * sum_p xp[n,c,ki+2pr,kj+2ps] * E2[n][c][p]
//  K3: per-n pronet (9 convs, residual blocks) on G_K = k - 0.1*gamma*G (flat), + normalize

__device__ __forceinline__ int refl(int m) {
    m = (m < 0) ? -m : m;
    return (m > 255) ? (510 - m) : m;
}

// ---------------- K1: blur + subtract y, store transposed E2 ----------------
// grid = 64 (n*c) * 16 (row blocks of 8) = 1024 blocks, 256 threads
// thread -> 1 row r, 4 consecutive ps outputs
__global__ __launch_bounds__(256) void blur_kernel(
        const float* __restrict__ x, const float* __restrict__ y,
        const float* __restrict__ kk, float* __restrict__ E2) {
    __shared__ float kl[121];
    int bid = blockIdx.x;
    int rowblk = bid & 15;
    int nc = bid >> 4;                 // n*8 + c
    int t = threadIdx.x;
    if (t < 121) kl[t] = kk[nc * 121 + t];
    __syncthreads();
    int r = rowblk * 8 + (t >> 5);     // output row 0..127
    int ps0 = (t & 31) * 4;            // output col base
    const float* xb = x + nc * 65536;
    float a0 = 0.f, a1 = 0.f, a2 = 0.f, a3 = 0.f;
    int cb = 2 * ps0 - 5;              // padded col base (pre-reflect)
    #pragma unroll
    for (int i = 0; i < 11; ++i) {
        int iy = refl(2 * r - 5 + i);
        const float* row = xb + iy * 256;
        float c[17];
        #pragma unroll
        for (int u = 0; u < 17; ++u) c[u] = row[refl(cb + u)];
        #pragma unroll
        for (int j = 0; j < 11; ++j) {
            float kv = kl[i * 11 + j];
            a0 = fmaf(c[j],     kv, a0);
            a1 = fmaf(c[j + 2], kv, a1);
            a2 = fmaf(c[j + 4], kv, a2);
            a3 = fmaf(c[j + 6], kv, a3);
        }
    }
    int n = nc >> 3;
    int o = nc * 16384 + r * 128 + ps0;          // flat [N][C][128][128]
    float4 yv = *reinterpret_cast<const float4*>(y + o);
    float e[4] = {a0 - yv.x, a1 - yv.y, a2 - yv.z, a3 - yv.w};
    // reinterpret flat-within-n index q as (p = q>>3, c' = q&7); store E2[n][c'][p]
    int qn = o - n * 131072;
    int p = qn >> 3;                   // same for all 4 (qn%8 in {0,4})
    int cbase = qn & 7;
    float* eb = E2 + n * 131072 + p;
    #pragma unroll
    for (int qq = 0; qq < 4; ++qq)
        eb[(cbase + qq) * 16384] = e[qq];
}

// ---------------- K2: G contraction ----------------
// grid = 64 (n*c) * 11 (ki) = 704 blocks, 256 threads
// thread: ps group of 4 (t&31), row subset pr = (t>>5) + 8*it, it=0..15
__global__ __launch_bounds__(256) void grad_kernel(
        const float* __restrict__ x, const float* __restrict__ E2,
        float* __restrict__ G) {
    int bid = blockIdx.x;
    int ki = bid % 11;
    int nc = bid / 11;
    int n = nc >> 3, c = nc & 7;
    const float* xb = x + nc * 65536;
    const float* Eb = E2 + n * 131072 + c * 16384;
    int t = threadIdx.x;
    int ps0 = (t & 31) * 4;
    int pr0 = t >> 5;
    int cb = 2 * ps0 - 5;
    float acc[11];
    #pragma unroll
    for (int j = 0; j < 11; ++j) acc[j] = 0.f;
    for (int it = 0; it < 16; ++it) {
        int pr = pr0 + (it << 3);
        int iy = refl(ki + 2 * pr - 5);
        const float* row = xb + iy * 256;
        float cbuf[17];
        #pragma unroll
        for (int u = 0; u < 17; ++u) cbuf[u] = row[refl(cb + u)];
        float4 ev = *reinterpret_cast<const float4*>(Eb + pr * 128 + ps0);
        #pragma unroll
        for (int j = 0; j < 11; ++j) {
            float v = acc[j];
            v = fmaf(cbuf[j],     ev.x, v);
            v = fmaf(cbuf[j + 2], ev.y, v);
            v = fmaf(cbuf[j + 4], ev.z, v);
            v = fmaf(cbuf[j + 6], ev.w, v);
            acc[j] = v;
        }
    }
    // block reduction: 4 waves
    __shared__ float part[4][11];
    int lane = t & 63, wid = t >> 6;
    #pragma unroll
    for (int j = 0; j < 11; ++j) {
        float v = acc[j];
        #pragma unroll
        for (int off = 32; off > 0; off >>= 1)
            v += __shfl_down(v, off, 64);
        if (lane == 0) part[wid][j] = v;
    }
    __syncthreads();
    if (t < 11) {
        float s = part[0][t] + part[1][t] + part[2][t] + part[3][t];
        G[n * 968 + (ki * 11 + t) * 8 + c] = s * (1.0f / 16384.0f);
    }
}

// ---------------- K3: pronet + normalize, one block per n ----------------
// block = 192 threads: 176 active = (half: ci 0-3 / 4-7) x (co 0..7) x (yy 0..10)
// padded planes [8][13][20] (row stride 20 floats: 16B-aligned + bank-spread),
// weights staged in LDS, per-thread row of 11 outputs with weights in registers.
// NOTE: launch MUST be 192 threads to match __launch_bounds__(192) — R2 failed
// because it launched 256 > bound (invalid config, silent no-op).
struct PArgs {
    const float* W[9];   // w1a,w1b,w2a,w2b,w3a,w3b,w4a,w4b,w5
    const float* B[9];
    const float* k;
    const float* gamma;
    const float* G;
    float* out;
};

#define PLSTRIDE 20

__device__ __forceinline__ void conv_partial(
        const float* __restrict__ Pin,   // padded plane base [8][13][PLSTRIDE]
        const float* __restrict__ w,     // weights for this co: [8 ci][9]
        int ci0, int yy, float* __restrict__ acc) {
    #pragma unroll
    for (int xx = 0; xx < 11; ++xx) acc[xx] = 0.f;
    #pragma unroll
    for (int cq = 0; cq < 4; ++cq) {
        int ci = ci0 + cq;
        const float* wp = w + ci * 9;
        float wv[9];
        #pragma unroll
        for (int q = 0; q < 9; ++q) wv[q] = wp[q];
        float r[3][13];
        #pragma unroll
        for (int dy = 0; dy < 3; ++dy) {
            const float* row = Pin + (ci * 13 + yy + dy) * PLSTRIDE;
            float4 a = *reinterpret_cast<const float4*>(row);
            float4 b = *reinterpret_cast<const float4*>(row + 4);
            float4 c = *reinterpret_cast<const float4*>(row + 8);
            r[dy][0] = a.x;  r[dy][1] = a.y;  r[dy][2]  = a.z;  r[dy][3]  = a.w;
            r[dy][4] = b.x;  r[dy][5] = b.y;  r[dy][6]  = b.z;  r[dy][7]  = b.w;
            r[dy][8] = c.x;  r[dy][9] = c.y;  r[dy][10] = c.z;  r[dy][11] = c.w;
            r[dy][12] = row[12];
        }
        #pragma unroll
        for (int xx = 0; xx < 11; ++xx) {
            float v = acc[xx];
            v = fmaf(r[0][xx],     wv[0], v);
            v = fmaf(r[0][xx + 1], wv[1], v);
            v = fmaf(r[0][xx + 2], wv[2], v);
            v = fmaf(r[1][xx],     wv[3], v);
            v = fmaf(r[1][xx + 1], wv[4], v);
            v = fmaf(r[1][xx + 2], wv[5], v);
            v = fmaf(r[2][xx],     wv[6], v);
            v = fmaf(r[2][xx + 1], wv[7], v);
            v = fmaf(r[2][xx + 2], wv[8], v);
            acc[xx] = v;
        }
    }
}

__global__ __launch_bounds__(192) void pronet_kernel(PArgs pa) {
    __shared__ __align__(16) float P0[8 * 13 * PLSTRIDE];
    __shared__ __align__(16) float P1[8 * 13 * PLSTRIDE];
    __shared__ float G2[968];
    __shared__ float F[968];
    __shared__ float red[88 * 11];
    __shared__ float wts[9 * 576];
    __shared__ float bs[9 * 8];
    __shared__ float rowsum[88];
    __shared__ float inv[8];

    int n = blockIdx.x;
    int t = threadIdx.x;

    // stage weights/biases into LDS
    #pragma unroll
    for (int cidx = 0; cidx < 9; ++cidx) {
        const float* wsrc = pa.W[cidx];
        for (int i = t; i < 576; i += 192) wts[cidx * 576 + i] = wsrc[i];
        if (t < 8) bs[cidx * 8 + t] = pa.B[cidx][t];
    }
    // zero padded planes
    for (int i = t; i < 8 * 13 * PLSTRIDE; i += 192) { P0[i] = 0.f; P1[i] = 0.f; }
    __syncthreads();

    float gm = pa.gamma[0] * 0.1f;
    for (int o = t; o < 968; o += 192) {
        // G_K flat reinterpretation: elementwise in flat order
        float v = pa.k[n * 968 + o] - gm * pa.G[n * 968 + o];
        G2[o] = v;
        int co = o / 121, rem = o - co * 121;
        int yy = rem / 11, xx = rem - yy * 11;
        P0[(co * 13 + yy + 1) * PLSTRIDE + xx + 1] = v;
    }

    bool active = t < 176;
    int half = t / 88;           // ci 0-3 vs 4-7
    int id = t - half * 88;      // 0..87
    int co = id / 11, yy = id - co * 11;
    int ci0 = half * 4;

    // mode 0: out = relu(conv)            -> P1
    // mode 1: out = relu(P0 + 0.1*conv)   -> P0   (residual close)
    // mode 2: out = relu(G2 + 0.1*conv)   -> F    (final conv5)
    auto do_conv = [&](const float* Pin, int widx, int mode) {
        __syncthreads();
        float acc[11];
        if (active) {
            conv_partial(Pin, &wts[widx * 576 + co * 72], ci0, yy, acc);
            if (half == 1) {
                #pragma unroll
                for (int xx = 0; xx < 11; ++xx) red[id * 11 + xx] = acc[xx];
            }
        }
        __syncthreads();
        if (active && half == 0) {
            float b = bs[widx * 8 + co];
            #pragma unroll
            for (int xx = 0; xx < 11; ++xx) {
                float v = acc[xx] + red[id * 11 + xx] + b;
                int pidx = (co * 13 + yy + 1) * PLSTRIDE + xx + 1;
                if (mode == 0) {
                    P1[pidx] = fmaxf(v, 0.f);
                } else if (mode == 1) {
                    float p = P0[pidx];
                    P0[pidx] = fmaxf(fmaf(0.1f, v, p), 0.f);
                } else {
                    int fo = co * 121 + yy * 11 + xx;
                    F[fo] = fmaxf(fmaf(0.1f, v, G2[fo]), 0.f);
                }
            }
        }
    };

    #pragma unroll
    for (int rb = 0; rb < 4; ++rb) {
        do_conv(P0, 2 * rb, 0);
        do_conv(P1, 2 * rb + 1, 1);
    }
    do_conv(P0, 8, 2);
    __syncthreads();

    if (t < 88) {
        int tco = t / 11, tyy = t - tco * 11;
        float s = 0.f;
        #pragma unroll
        for (int xx = 0; xx < 11; ++xx) s += F[tco * 121 + tyy * 11 + xx];
        rowsum[t] = s;
    }
    __syncthreads();
    if (t < 8) {
        float s = 0.f;
        #pragma unroll
        for (int j = 0; j < 11; ++j) s += rowsum[t * 11 + j];
        inv[t] = 1.f / s;
    }
    __syncthreads();
    for (int o = t; o < 968; o += 192)
        pa.out[n * 968 + o] = F[o] * inv[o / 121];
}

extern "C" void kernel_launch(void* const* d_in, const int* in_sizes, int n_in,
                              void* d_out, int out_size, void* d_ws, size_t ws_size,
                              hipStream_t stream) {
    const float* x = (const float*)d_in[0];
    const float* y = (const float*)d_in[1];
    const float* k = (const float*)d_in[2];
    // d_in[3] = sf (int, constant 2) — unused
    const float* gamma = (const float*)d_in[4];

    float* E2 = (float*)d_ws;            // 8*131072 floats = 4 MB
    float* G  = E2 + 8 * 131072;         // 7744 floats

    blur_kernel<<<1024, 256, 0, stream>>>(x, y, k, E2);
    grad_kernel<<<704, 256, 0, stream>>>(x, E2, G);

    PArgs pa;
    for (int i = 0; i < 9; ++i) {
        pa.W[i] = (const float*)d_in[5 + 2 * i];
        pa.B[i] = (const float*)d_in[6 + 2 * i];
    }
    pa.k = k;
    pa.gamma = gamma;
    pa.G = G;
    pa.out = (float*)d_out;
    pronet_kernel<<<8, 192, 0, stream>>>(pa);
}

// Round 4
// 176.631 us; speedup vs baseline: 2.3841x; 1.3123x over previous
//
#include <hip/hip_runtime.h>

// MTFNet: N=8, C=8, H=W=256, L=11, SF=2, h=w=128
// Pipeline:
//  K0: xpad[nc][256][272] = column-reflect-padded x (halo 8 each side) -> all
//      window loads in K1/K2 become aligned float4, branch-free
//  K1: E2[n][c'][p] = (blur(x,k) - y) stored via flat reinterpret (p*8+c' = flat(C,h,w))
//  K2: G[n][ki*11+kj][c] = (1/16384) * sum_p xp[n,c,ki+2pr,kj+2ps] * E2[n][c][p]
//  K3: per-n pronet (9 convs, residual blocks) on G_K = k - 0.1*gamma*G (flat), + normalize
// Fallback (ws too small for xpad): R3's scalar-load blur/grad (known-good).

__device__ __forceinline__ int refl(int m) {
    m = (m < 0) ? -m : m;
    return (m > 255) ? (510 - m) : m;
}

#define XPROW 272   // 256 + 8 halo each side

// ---------------- K0: column-pad x with reflection ----------------
// grid = 64 nc * 4 row-chunks, 256 threads = 4 row-teams of 64 lanes
__global__ __launch_bounds__(256) void pad_kernel(
        const float* __restrict__ x, float* __restrict__ xp) {
    int bid = blockIdx.x;
    int chunk = bid & 3;
    int nc = bid >> 2;
    int team = threadIdx.x >> 6;
    int lane = threadIdx.x & 63;
    const float* xb = x + nc * 65536;
    float* xpb = xp + nc * (256 * XPROW);
    for (int it = 0; it < 16; ++it) {
        int row = chunk * 64 + it * 4 + team;
        const float* src = xb + row * 256;
        float* dst = xpb + row * XPROW + 8;
        float4 v = reinterpret_cast<const float4*>(src)[lane];
        reinterpret_cast<float4*>(dst)[lane] = v;
        if (lane < 8) {
            dst[-1 - lane] = src[1 + lane];              // col -1-lane -> refl 1+lane
        } else if (lane < 16) {
            int j = lane - 8;
            dst[256 + j] = src[254 - j];                 // col 256+j -> refl 254-j
        }
    }
}

// ---------------- K1: blur + subtract y, store transposed E2 (padded loads) --
// grid = 64 (n*c) * 16 (row blocks of 8) = 1024 blocks, 256 threads
__global__ __launch_bounds__(256) void blur_kernel(
        const float* __restrict__ xp, const float* __restrict__ y,
        const float* __restrict__ kk, float* __restrict__ E2) {
    __shared__ float kl[121];
    int bid = blockIdx.x;
    int rowblk = bid & 15;
    int nc = bid >> 4;
    int t = threadIdx.x;
    if (t < 121) kl[t] = kk[nc * 121 + t];
    __syncthreads();
    int r = rowblk * 8 + (t >> 5);
    int ps0 = (t & 31) * 4;
    const float* xb = xp + nc * (256 * XPROW);
    float a0 = 0.f, a1 = 0.f, a2 = 0.f, a3 = 0.f;
    #pragma unroll
    for (int i = 0; i < 11; ++i) {
        int iy = refl(2 * r - 5 + i);
        // stored offset 2*ps0 = actual col 2*ps0-8; window covers cols 2ps0-8..2ps0+15
        const float4* row4 = reinterpret_cast<const float4*>(xb + iy * XPROW + 2 * ps0);
        float w[24];
        #pragma unroll
        for (int q = 0; q < 6; ++q) {
            float4 v = row4[q];
            w[4 * q] = v.x; w[4 * q + 1] = v.y; w[4 * q + 2] = v.z; w[4 * q + 3] = v.w;
        }
        #pragma unroll
        for (int j = 0; j < 11; ++j) {
            float kv = kl[i * 11 + j];
            a0 = fmaf(w[j + 3], kv, a0);
            a1 = fmaf(w[j + 5], kv, a1);
            a2 = fmaf(w[j + 7], kv, a2);
            a3 = fmaf(w[j + 9], kv, a3);
        }
    }
    int n = nc >> 3;
    int o = nc * 16384 + r * 128 + ps0;
    float4 yv = *reinterpret_cast<const float4*>(y + o);
    float e[4] = {a0 - yv.x, a1 - yv.y, a2 - yv.z, a3 - yv.w};
    int qn = o - n * 131072;
    int p = qn >> 3;
    int cbase = qn & 7;
    float* eb = E2 + n * 131072 + p;
    #pragma unroll
    for (int qq = 0; qq < 4; ++qq)
        eb[(cbase + qq) * 16384] = e[qq];
}

// ---------------- K2: G contraction (padded loads) ----------------
// grid = 64 (n*c) * 11 (ki) = 704 blocks, 256 threads
__global__ __launch_bounds__(256) void grad_kernel(
        const float* __restrict__ xp, const float* __restrict__ E2,
        float* __restrict__ G) {
    int bid = blockIdx.x;
    int ki = bid % 11;
    int nc = bid / 11;
    int n = nc >> 3, c = nc & 7;
    const float* xb = xp + nc * (256 * XPROW);
    const float* Eb = E2 + n * 131072 + c * 16384;
    int t = threadIdx.x;
    int ps0 = (t & 31) * 4;
    int pr0 = t >> 5;
    float acc[11];
    #pragma unroll
    for (int j = 0; j < 11; ++j) acc[j] = 0.f;
    for (int it = 0; it < 16; ++it) {
        int pr = pr0 + (it << 3);
        int iy = refl(ki + 2 * pr - 5);
        float4 ev = *reinterpret_cast<const float4*>(Eb + pr * 128 + ps0);
        const float4* row4 = reinterpret_cast<const float4*>(xb + iy * XPROW + 2 * ps0);
        float w[24];
        #pragma unroll
        for (int q = 0; q < 6; ++q) {
            float4 v = row4[q];
            w[4 * q] = v.x; w[4 * q + 1] = v.y; w[4 * q + 2] = v.z; w[4 * q + 3] = v.w;
        }
        #pragma unroll
        for (int j = 0; j < 11; ++j) {
            float v = acc[j];
            v = fmaf(w[j + 3], ev.x, v);
            v = fmaf(w[j + 5], ev.y, v);
            v = fmaf(w[j + 7], ev.z, v);
            v = fmaf(w[j + 9], ev.w, v);
            acc[j] = v;
        }
    }
    __shared__ float part[4][11];
    int lane = t & 63, wid = t >> 6;
    #pragma unroll
    for (int j = 0; j < 11; ++j) {
        float v = acc[j];
        #pragma unroll
        for (int off = 32; off > 0; off >>= 1)
            v += __shfl_down(v, off, 64);
        if (lane == 0) part[wid][j] = v;
    }
    __syncthreads();
    if (t < 11) {
        float s = part[0][t] + part[1][t] + part[2][t] + part[3][t];
        G[n * 968 + (ki * 11 + t) * 8 + c] = s * (1.0f / 16384.0f);
    }
}

// ---------------- Fallback kernels (R3, scalar loads, known-good) ----------
__global__ __launch_bounds__(256) void blur_kernel_ref(
        const float* __restrict__ x, const float* __restrict__ y,
        const float* __restrict__ kk, float* __restrict__ E2) {
    __shared__ float kl[121];
    int bid = blockIdx.x;
    int rowblk = bid & 15;
    int nc = bid >> 4;
    int t = threadIdx.x;
    if (t < 121) kl[t] = kk[nc * 121 + t];
    __syncthreads();
    int r = rowblk * 8 + (t >> 5);
    int ps0 = (t & 31) * 4;
    const float* xb = x + nc * 65536;
    float a0 = 0.f, a1 = 0.f, a2 = 0.f, a3 = 0.f;
    int cb = 2 * ps0 - 5;
    #pragma unroll
    for (int i = 0; i < 11; ++i) {
        int iy = refl(2 * r - 5 + i);
        const float* row = xb + iy * 256;
        float c[17];
        #pragma unroll
        for (int u = 0; u < 17; ++u) c[u] = row[refl(cb + u)];
        #pragma unroll
        for (int j = 0; j < 11; ++j) {
            float kv = kl[i * 11 + j];
            a0 = fmaf(c[j], kv, a0);
            a1 = fmaf(c[j + 2], kv, a1);
            a2 = fmaf(c[j + 4], kv, a2);
            a3 = fmaf(c[j + 6], kv, a3);
        }
    }
    int n = nc >> 3;
    int o = nc * 16384 + r * 128 + ps0;
    float4 yv = *reinterpret_cast<const float4*>(y + o);
    float e[4] = {a0 - yv.x, a1 - yv.y, a2 - yv.z, a3 - yv.w};
    int qn = o - n * 131072;
    int p = qn >> 3;
    int cbase = qn & 7;
    float* eb = E2 + n * 131072 + p;
    #pragma unroll
    for (int qq = 0; qq < 4; ++qq)
        eb[(cbase + qq) * 16384] = e[qq];
}

__global__ __launch_bounds__(256) void grad_kernel_ref(
        const float* __restrict__ x, const float* __restrict__ E2,
        float* __restrict__ G) {
    int bid = blockIdx.x;
    int ki = bid % 11;
    int nc = bid / 11;
    int n = nc >> 3, c = nc & 7;
    const float* xb = x + nc * 65536;
    const float* Eb = E2 + n * 131072 + c * 16384;
    int t = threadIdx.x;
    int ps0 = (t & 31) * 4;
    int pr0 = t >> 5;
    int cb = 2 * ps0 - 5;
    float acc[11];
    #pragma unroll
    for (int j = 0; j < 11; ++j) acc[j] = 0.f;
    for (int it = 0; it < 16; ++it) {
        int pr = pr0 + (it << 3);
        int iy = refl(ki + 2 * pr - 5);
        const float* row = xb + iy * 256;
        float cbuf[17];
        #pragma unroll
        for (int u = 0; u < 17; ++u) cbuf[u] = row[refl(cb + u)];
        float4 ev = *reinterpret_cast<const float4*>(Eb + pr * 128 + ps0);
        #pragma unroll
        for (int j = 0; j < 11; ++j) {
            float v = acc[j];
            v = fmaf(cbuf[j], ev.x, v);
            v = fmaf(cbuf[j + 2], ev.y, v);
            v = fmaf(cbuf[j + 4], ev.z, v);
            v = fmaf(cbuf[j + 6], ev.w, v);
            acc[j] = v;
        }
    }
    __shared__ float part[4][11];
    int lane = t & 63, wid = t >> 6;
    #pragma unroll
    for (int j = 0; j < 11; ++j) {
        float v = acc[j];
        #pragma unroll
        for (int off = 32; off > 0; off >>= 1)
            v += __shfl_down(v, off, 64);
        if (lane == 0) part[wid][j] = v;
    }
    __syncthreads();
    if (t < 11) {
        float s = part[0][t] + part[1][t] + part[2][t] + part[3][t];
        G[n * 968 + (ki * 11 + t) * 8 + c] = s * (1.0f / 16384.0f);
    }
}

// ---------------- K3: pronet + normalize, one block per n ----------------
// block = 192 threads: 176 active = (half: ci 0-3 / 4-7) x (co 0..7) x (yy 0..10)
// NOTE: launch MUST be 192 threads (== __launch_bounds__); 256 silently no-ops.
struct PArgs {
    const float* W[9];
    const float* B[9];
    const float* k;
    const float* gamma;
    const float* G;
    float* out;
};

#define PLSTRIDE 20

__device__ __forceinline__ void conv_partial(
        const float* __restrict__ Pin,
        const float* __restrict__ w,
        int ci0, int yy, float* __restrict__ acc) {
    #pragma unroll
    for (int xx = 0; xx < 11; ++xx) acc[xx] = 0.f;
    #pragma unroll
    for (int cq = 0; cq < 4; ++cq) {
        int ci = ci0 + cq;
        const float* wp = w + ci * 9;
        float wv[9];
        #pragma unroll
        for (int q = 0; q < 9; ++q) wv[q] = wp[q];
        float r[3][13];
        #pragma unroll
        for (int dy = 0; dy < 3; ++dy) {
            const float* row = Pin + (ci * 13 + yy + dy) * PLSTRIDE;
            float4 a = *reinterpret_cast<const float4*>(row);
            float4 b = *reinterpret_cast<const float4*>(row + 4);
            float4 c = *reinterpret_cast<const float4*>(row + 8);
            r[dy][0] = a.x;  r[dy][1] = a.y;  r[dy][2]  = a.z;  r[dy][3]  = a.w;
            r[dy][4] = b.x;  r[dy][5] = b.y;  r[dy][6]  = b.z;  r[dy][7]  = b.w;
            r[dy][8] = c.x;  r[dy][9] = c.y;  r[dy][10] = c.z;  r[dy][11] = c.w;
            r[dy][12] = row[12];
        }
        #pragma unroll
        for (int xx = 0; xx < 11; ++xx) {
            float v = acc[xx];
            v = fmaf(r[0][xx],     wv[0], v);
            v = fmaf(r[0][xx + 1], wv[1], v);
            v = fmaf(r[0][xx + 2], wv[2], v);
            v = fmaf(r[1][xx],     wv[3], v);
            v = fmaf(r[1][xx + 1], wv[4], v);
            v = fmaf(r[1][xx + 2], wv[5], v);
            v = fmaf(r[2][xx],     wv[6], v);
            v = fmaf(r[2][xx + 1], wv[7], v);
            v = fmaf(r[2][xx + 2], wv[8], v);
            acc[xx] = v;
        }
    }
}

__global__ __launch_bounds__(192) void pronet_kernel(PArgs pa) {
    __shared__ __align__(16) float P0[8 * 13 * PLSTRIDE];
    __shared__ __align__(16) float P1[8 * 13 * PLSTRIDE];
    __shared__ float G2[968];
    __shared__ float F[968];
    __shared__ float red[88 * 11];
    __shared__ float wts[9 * 576];
    __shared__ float bs[9 * 8];
    __shared__ float rowsum[88];
    __shared__ float inv[8];

    int n = blockIdx.x;
    int t = threadIdx.x;

    #pragma unroll
    for (int cidx = 0; cidx < 9; ++cidx) {
        const float* wsrc = pa.W[cidx];
        for (int i = t; i < 576; i += 192) wts[cidx * 576 + i] = wsrc[i];
        if (t < 8) bs[cidx * 8 + t] = pa.B[cidx][t];
    }
    for (int i = t; i < 8 * 13 * PLSTRIDE; i += 192) { P0[i] = 0.f; P1[i] = 0.f; }
    __syncthreads();

    float gm = pa.gamma[0] * 0.1f;
    for (int o = t; o < 968; o += 192) {
        float v = pa.k[n * 968 + o] - gm * pa.G[n * 968 + o];
        G2[o] = v;
        int co = o / 121, rem = o - co * 121;
        int yy = rem / 11, xx = rem - yy * 11;
        P0[(co * 13 + yy + 1) * PLSTRIDE + xx + 1] = v;
    }

    bool active = t < 176;
    int half = t / 88;
    int id = t - half * 88;
    int co = id / 11, yy = id - co * 11;
    int ci0 = half * 4;

    auto do_conv = [&](const float* Pin, int widx, int mode) {
        __syncthreads();
        float acc[11];
        if (active) {
            conv_partial(Pin, &wts[widx * 576 + co * 72], ci0, yy, acc);
            if (half == 1) {
                #pragma unroll
                for (int xx = 0; xx < 11; ++xx) red[id * 11 + xx] = acc[xx];
            }
        }
        __syncthreads();
        if (active && half == 0) {
            float b = bs[widx * 8 + co];
            #pragma unroll
            for (int xx = 0; xx < 11; ++xx) {
                float v = acc[xx] + red[id * 11 + xx] + b;
                int pidx = (co * 13 + yy + 1) * PLSTRIDE + xx + 1;
                if (mode == 0) {
                    P1[pidx] = fmaxf(v, 0.f);
                } else if (mode == 1) {
                    float p = P0[pidx];
                    P0[pidx] = fmaxf(fmaf(0.1f, v, p), 0.f);
                } else {
                    int fo = co * 121 + yy * 11 + xx;
                    F[fo] = fmaxf(fmaf(0.1f, v, G2[fo]), 0.f);
                }
            }
        }
    };

    #pragma unroll
    for (int rb = 0; rb < 4; ++rb) {
        do_conv(P0, 2 * rb, 0);
        do_conv(P1, 2 * rb + 1, 1);
    }
    do_conv(P0, 8, 2);
    __syncthreads();

    if (t < 88) {
        int tco = t / 11, tyy = t - tco * 11;
        float s = 0.f;
        #pragma unroll
        for (int xx = 0; xx < 11; ++xx) s += F[tco * 121 + tyy * 11 + xx];
        rowsum[t] = s;
    }
    __syncthreads();
    if (t < 8) {
        float s = 0.f;
        #pragma unroll
        for (int j = 0; j < 11; ++j) s += rowsum[t * 11 + j];
        inv[t] = 1.f / s;
    }
    __syncthreads();
    for (int o = t; o < 968; o += 192)
        pa.out[n * 968 + o] = F[o] * inv[o / 121];
}

extern "C" void kernel_launch(void* const* d_in, const int* in_sizes, int n_in,
                              void* d_out, int out_size, void* d_ws, size_t ws_size,
                              hipStream_t stream) {
    const float* x = (const float*)d_in[0];
    const float* y = (const float*)d_in[1];
    const float* k = (const float*)d_in[2];
    const float* gamma = (const float*)d_in[4];

    // ws layout: [xpad 64*256*272][E2 8*131072][G 7744]
    const size_t xpad_fl = (size_t)64 * 256 * XPROW;          // 17,825,792 B
    const size_t e2_fl = (size_t)8 * 131072;                  //  4,194,304 B
    const size_t need = (xpad_fl + e2_fl + 7744) * sizeof(float);

    float* G;
    if (ws_size >= need) {
        float* xpad = (float*)d_ws;
        float* E2 = xpad + xpad_fl;
        G = E2 + e2_fl;
        pad_kernel<<<256, 256, 0, stream>>>(x, xpad);
        blur_kernel<<<1024, 256, 0, stream>>>(xpad, y, k, E2);
        grad_kernel<<<704, 256, 0, stream>>>(xpad, E2, G);
    } else {
        float* E2 = (float*)d_ws;
        G = E2 + e2_fl;
        blur_kernel_ref<<<1024, 256, 0, stream>>>(x, y, k, E2);
        grad_kernel_ref<<<704, 256, 0, stream>>>(x, E2, G);
    }

    PArgs pa;
    for (int i = 0; i < 9; ++i) {
        pa.W[i] = (const float*)d_in[5 + 2 * i];
        pa.B[i] = (const float*)d_in[6 + 2 * i];
    }
    pa.k = k;
    pa.gamma = gamma;
    pa.G = G;
    pa.out = (float*)d_out;
    pronet_kernel<<<8, 192, 0, stream>>>(pa);
}

// Round 5
// 174.986 us; speedup vs baseline: 2.4065x; 1.0094x over previous
//
#include <hip/hip_runtime.h>

// MTFNet: N=8, C=8, H=W=256, L=11, SF=2, h=w=128
// Pipeline:
//  K0: xpad[nc][256][272] = column-reflect-padded x (halo 8 each side)
//  K1: E2[n][c'][p] = (blur(x,k) - y) stored via flat reinterpret (p*8+c' = flat(C,h,w))
//  K2: G[n][ki*11+kj][c] = (1/16384) * sum_p xp[n,c,ki+2pr,kj+2ps] * E2[n][c][p]
//  K3: per-n pronet (9 convs, residual blocks) on G_K = k - 0.1*gamma*G (flat), + normalize
//      v3: 352 active threads (4-way ci split), b128 weight loads, vectorized reduction
// Fallback (ws too small for xpad): R3's scalar-load blur/grad (known-good).
// NOTE: dur_us includes ~100 us of harness reset (268MB ws poison + input restore) —
// controllable floor is ~120 us.

__device__ __forceinline__ int refl(int m) {
    m = (m < 0) ? -m : m;
    return (m > 255) ? (510 - m) : m;
}

#define XPROW 272   // 256 + 8 halo each side

// ---------------- K0: column-pad x with reflection ----------------
__global__ __launch_bounds__(256) void pad_kernel(
        const float* __restrict__ x, float* __restrict__ xp) {
    int bid = blockIdx.x;
    int chunk = bid & 3;
    int nc = bid >> 2;
    int team = threadIdx.x >> 6;
    int lane = threadIdx.x & 63;
    const float* xb = x + nc * 65536;
    float* xpb = xp + nc * (256 * XPROW);
    for (int it = 0; it < 16; ++it) {
        int row = chunk * 64 + it * 4 + team;
        const float* src = xb + row * 256;
        float* dst = xpb + row * XPROW + 8;
        float4 v = reinterpret_cast<const float4*>(src)[lane];
        reinterpret_cast<float4*>(dst)[lane] = v;
        if (lane < 8) {
            dst[-1 - lane] = src[1 + lane];
        } else if (lane < 16) {
            int j = lane - 8;
            dst[256 + j] = src[254 - j];
        }
    }
}

// ---------------- K1: blur + subtract y, store transposed E2 (padded loads) --
__global__ __launch_bounds__(256) void blur_kernel(
        const float* __restrict__ xp, const float* __restrict__ y,
        const float* __restrict__ kk, float* __restrict__ E2) {
    __shared__ float kl[121];
    int bid = blockIdx.x;
    int rowblk = bid & 15;
    int nc = bid >> 4;
    int t = threadIdx.x;
    if (t < 121) kl[t] = kk[nc * 121 + t];
    __syncthreads();
    int r = rowblk * 8 + (t >> 5);
    int ps0 = (t & 31) * 4;
    const float* xb = xp + nc * (256 * XPROW);
    float a0 = 0.f, a1 = 0.f, a2 = 0.f, a3 = 0.f;
    #pragma unroll
    for (int i = 0; i < 11; ++i) {
        int iy = refl(2 * r - 5 + i);
        const float4* row4 = reinterpret_cast<const float4*>(xb + iy * XPROW + 2 * ps0);
        float w[24];
        #pragma unroll
        for (int q = 0; q < 6; ++q) {
            float4 v = row4[q];
            w[4 * q] = v.x; w[4 * q + 1] = v.y; w[4 * q + 2] = v.z; w[4 * q + 3] = v.w;
        }
        #pragma unroll
        for (int j = 0; j < 11; ++j) {
            float kv = kl[i * 11 + j];
            a0 = fmaf(w[j + 3], kv, a0);
            a1 = fmaf(w[j + 5], kv, a1);
            a2 = fmaf(w[j + 7], kv, a2);
            a3 = fmaf(w[j + 9], kv, a3);
        }
    }
    int n = nc >> 3;
    int o = nc * 16384 + r * 128 + ps0;
    float4 yv = *reinterpret_cast<const float4*>(y + o);
    float e[4] = {a0 - yv.x, a1 - yv.y, a2 - yv.z, a3 - yv.w};
    int qn = o - n * 131072;
    int p = qn >> 3;
    int cbase = qn & 7;
    float* eb = E2 + n * 131072 + p;
    #pragma unroll
    for (int qq = 0; qq < 4; ++qq)
        eb[(cbase + qq) * 16384] = e[qq];
}

// ---------------- K2: G contraction (padded loads) ----------------
__global__ __launch_bounds__(256) void grad_kernel(
        const float* __restrict__ xp, const float* __restrict__ E2,
        float* __restrict__ G) {
    int bid = blockIdx.x;
    int ki = bid % 11;
    int nc = bid / 11;
    int n = nc >> 3, c = nc & 7;
    const float* xb = xp + nc * (256 * XPROW);
    const float* Eb = E2 + n * 131072 + c * 16384;
    int t = threadIdx.x;
    int ps0 = (t & 31) * 4;
    int pr0 = t >> 5;
    float acc[11];
    #pragma unroll
    for (int j = 0; j < 11; ++j) acc[j] = 0.f;
    for (int it = 0; it < 16; ++it) {
        int pr = pr0 + (it << 3);
        int iy = refl(ki + 2 * pr - 5);
        float4 ev = *reinterpret_cast<const float4*>(Eb + pr * 128 + ps0);
        const float4* row4 = reinterpret_cast<const float4*>(xb + iy * XPROW + 2 * ps0);
        float w[24];
        #pragma unroll
        for (int q = 0; q < 6; ++q) {
            float4 v = row4[q];
            w[4 * q] = v.x; w[4 * q + 1] = v.y; w[4 * q + 2] = v.z; w[4 * q + 3] = v.w;
        }
        #pragma unroll
        for (int j = 0; j < 11; ++j) {
            float v = acc[j];
            v = fmaf(w[j + 3], ev.x, v);
            v = fmaf(w[j + 5], ev.y, v);
            v = fmaf(w[j + 7], ev.z, v);
            v = fmaf(w[j + 9], ev.w, v);
            acc[j] = v;
        }
    }
    __shared__ float part[4][11];
    int lane = t & 63, wid = t >> 6;
    #pragma unroll
    for (int j = 0; j < 11; ++j) {
        float v = acc[j];
        #pragma unroll
        for (int off = 32; off > 0; off >>= 1)
            v += __shfl_down(v, off, 64);
        if (lane == 0) part[wid][j] = v;
    }
    __syncthreads();
    if (t < 11) {
        float s = part[0][t] + part[1][t] + part[2][t] + part[3][t];
        G[n * 968 + (ki * 11 + t) * 8 + c] = s * (1.0f / 16384.0f);
    }
}

// ---------------- Fallback kernels (R3, scalar loads, known-good) ----------
__global__ __launch_bounds__(256) void blur_kernel_ref(
        const float* __restrict__ x, const float* __restrict__ y,
        const float* __restrict__ kk, float* __restrict__ E2) {
    __shared__ float kl[121];
    int bid = blockIdx.x;
    int rowblk = bid & 15;
    int nc = bid >> 4;
    int t = threadIdx.x;
    if (t < 121) kl[t] = kk[nc * 121 + t];
    __syncthreads();
    int r = rowblk * 8 + (t >> 5);
    int ps0 = (t & 31) * 4;
    const float* xb = x + nc * 65536;
    float a0 = 0.f, a1 = 0.f, a2 = 0.f, a3 = 0.f;
    int cb = 2 * ps0 - 5;
    #pragma unroll
    for (int i = 0; i < 11; ++i) {
        int iy = refl(2 * r - 5 + i);
        const float* row = xb + iy * 256;
        float c[17];
        #pragma unroll
        for (int u = 0; u < 17; ++u) c[u] = row[refl(cb + u)];
        #pragma unroll
        for (int j = 0; j < 11; ++j) {
            float kv = kl[i * 11 + j];
            a0 = fmaf(c[j], kv, a0);
            a1 = fmaf(c[j + 2], kv, a1);
            a2 = fmaf(c[j + 4], kv, a2);
            a3 = fmaf(c[j + 6], kv, a3);
        }
    }
    int n = nc >> 3;
    int o = nc * 16384 + r * 128 + ps0;
    float4 yv = *reinterpret_cast<const float4*>(y + o);
    float e[4] = {a0 - yv.x, a1 - yv.y, a2 - yv.z, a3 - yv.w};
    int qn = o - n * 131072;
    int p = qn >> 3;
    int cbase = qn & 7;
    float* eb = E2 + n * 131072 + p;
    #pragma unroll
    for (int qq = 0; qq < 4; ++qq)
        eb[(cbase + qq) * 16384] = e[qq];
}

__global__ __launch_bounds__(256) void grad_kernel_ref(
        const float* __restrict__ x, const float* __restrict__ E2,
        float* __restrict__ G) {
    int bid = blockIdx.x;
    int ki = bid % 11;
    int nc = bid / 11;
    int n = nc >> 3, c = nc & 7;
    const float* xb = x + nc * 65536;
    const float* Eb = E2 + n * 131072 + c * 16384;
    int t = threadIdx.x;
    int ps0 = (t & 31) * 4;
    int pr0 = t >> 5;
    int cb = 2 * ps0 - 5;
    float acc[11];
    #pragma unroll
    for (int j = 0; j < 11; ++j) acc[j] = 0.f;
    for (int it = 0; it < 16; ++it) {
        int pr = pr0 + (it << 3);
        int iy = refl(ki + 2 * pr - 5);
        const float* row = xb + iy * 256;
        float cbuf[17];
        #pragma unroll
        for (int u = 0; u < 17; ++u) cbuf[u] = row[refl(cb + u)];
        float4 ev = *reinterpret_cast<const float4*>(Eb + pr * 128 + ps0);
        #pragma unroll
        for (int j = 0; j < 11; ++j) {
            float v = acc[j];
            v = fmaf(cbuf[j], ev.x, v);
            v = fmaf(cbuf[j + 2], ev.y, v);
            v = fmaf(cbuf[j + 4], ev.z, v);
            v = fmaf(cbuf[j + 6], ev.w, v);
            acc[j] = v;
        }
    }
    __shared__ float part[4][11];
    int lane = t & 63, wid = t >> 6;
    #pragma unroll
    for (int j = 0; j < 11; ++j) {
        float v = acc[j];
        #pragma unroll
        for (int off = 32; off > 0; off >>= 1)
            v += __shfl_down(v, off, 64);
        if (lane == 0) part[wid][j] = v;
    }
    __syncthreads();
    if (t < 11) {
        float s = part[0][t] + part[1][t] + part[2][t] + part[3][t];
        G[n * 968 + (ki * 11 + t) * 8 + c] = s * (1.0f / 16384.0f);
    }
}

// ---------------- K3: pronet v3 ----------------
// 384 threads (352 active = quarter 0..3 x co 0..7 x yy 0..10), 2 ci per thread.
// Weights padded to 12 floats/(co,ci) in LDS -> 3 x ds_read_b128 per ci.
// Partial sums exchanged via red[3][88][12] with float4 writes/reads.
struct PArgs {
    const float* W[9];
    const float* B[9];
    const float* k;
    const float* gamma;
    const float* G;
    float* out;
};

#define PLSTRIDE 20
#define WSTRIDE 12

__global__ __launch_bounds__(384) void pronet_kernel(PArgs pa) {
    __shared__ __align__(16) float P0[8 * 13 * PLSTRIDE];
    __shared__ __align__(16) float P1[8 * 13 * PLSTRIDE];
    __shared__ float G2[968];
    __shared__ float F[968];
    __shared__ __align__(16) float red[3 * 88 * WSTRIDE];
    __shared__ __align__(16) float wts[9 * 64 * WSTRIDE];
    __shared__ float bs[9 * 8];
    __shared__ float rowsum[88];
    __shared__ float inv[8];

    int n = blockIdx.x;
    int t = threadIdx.x;

    // stage weights padded: wts[(widx*64 + co*8+ci)*12 + q] = W[widx][(co*8+ci)*9 + q]
    #pragma unroll
    for (int widx = 0; widx < 9; ++widx) {
        const float* wsrc = pa.W[widx];
        for (int i = t; i < 576; i += 384) {
            int oc = i / 9, q = i - oc * 9;
            wts[(widx * 64 + oc) * WSTRIDE + q] = wsrc[i];
        }
        if (t < 8) bs[widx * 8 + t] = pa.B[widx][t];
    }
    for (int i = t; i < 8 * 13 * PLSTRIDE; i += 384) { P0[i] = 0.f; P1[i] = 0.f; }
    __syncthreads();

    float gm = pa.gamma[0] * 0.1f;
    for (int o = t; o < 968; o += 384) {
        float v = pa.k[n * 968 + o] - gm * pa.G[n * 968 + o];
        G2[o] = v;
        int co = o / 121, rem = o - co * 121;
        int yy = rem / 11, xx = rem - yy * 11;
        P0[(co * 13 + yy + 1) * PLSTRIDE + xx + 1] = v;
    }

    bool active = t < 352;
    int quarter = t / 88;            // 0..3 -> ci {2q, 2q+1}
    int id = t - quarter * 88;       // 0..87
    int co = id / 11, yy = id - co * 11;
    int ci0 = quarter * 2;

    // mode 0: P1 = relu(conv);  mode 1: P0 = relu(P0 + 0.1*conv);
    // mode 2: F  = relu(G2 + 0.1*conv)
    auto do_conv = [&](const float* Pin, int widx, int mode) {
        __syncthreads();
        float acc[12];
        if (active) {
            #pragma unroll
            for (int xx = 0; xx < 12; ++xx) acc[xx] = 0.f;
            #pragma unroll
            for (int cq = 0; cq < 2; ++cq) {
                int ci = ci0 + cq;
                const float4* wp4 = reinterpret_cast<const float4*>(
                    &wts[(widx * 64 + co * 8 + ci) * WSTRIDE]);
                float4 w0 = wp4[0], w1 = wp4[1], w2 = wp4[2];
                float wv[9] = {w0.x, w0.y, w0.z, w0.w, w1.x, w1.y, w1.z, w1.w, w2.x};
                float r[3][13];
                #pragma unroll
                for (int dy = 0; dy < 3; ++dy) {
                    const float* row = Pin + (ci * 13 + yy + dy) * PLSTRIDE;
                    float4 a = *reinterpret_cast<const float4*>(row);
                    float4 b = *reinterpret_cast<const float4*>(row + 4);
                    float4 c = *reinterpret_cast<const float4*>(row + 8);
                    r[dy][0] = a.x;  r[dy][1] = a.y;  r[dy][2]  = a.z;  r[dy][3]  = a.w;
                    r[dy][4] = b.x;  r[dy][5] = b.y;  r[dy][6]  = b.z;  r[dy][7]  = b.w;
                    r[dy][8] = c.x;  r[dy][9] = c.y;  r[dy][10] = c.z;  r[dy][11] = c.w;
                    r[dy][12] = row[12];
                }
                #pragma unroll
                for (int xx = 0; xx < 11; ++xx) {
                    float v = acc[xx];
                    v = fmaf(r[0][xx],     wv[0], v);
                    v = fmaf(r[0][xx + 1], wv[1], v);
                    v = fmaf(r[0][xx + 2], wv[2], v);
                    v = fmaf(r[1][xx],     wv[3], v);
                    v = fmaf(r[1][xx + 1], wv[4], v);
                    v = fmaf(r[1][xx + 2], wv[5], v);
                    v = fmaf(r[2][xx],     wv[6], v);
                    v = fmaf(r[2][xx + 1], wv[7], v);
                    v = fmaf(r[2][xx + 2], wv[8], v);
                    acc[xx] = v;
                }
            }
            if (quarter != 0) {
                float4* rp = reinterpret_cast<float4*>(
                    &red[((quarter - 1) * 88 + id) * WSTRIDE]);
                rp[0] = make_float4(acc[0], acc[1], acc[2],  acc[3]);
                rp[1] = make_float4(acc[4], acc[5], acc[6],  acc[7]);
                rp[2] = make_float4(acc[8], acc[9], acc[10], acc[11]);
            }
        }
        __syncthreads();
        if (active && quarter == 0) {
            float b = bs[widx * 8 + co];
            float oth[12];
            #pragma unroll
            for (int pq = 0; pq < 3; ++pq) {
                const float4* rp = reinterpret_cast<const float4*>(
                    &red[(pq * 88 + id) * WSTRIDE]);
                float4 v0 = rp[0], v1 = rp[1], v2 = rp[2];
                if (pq == 0) {
                    oth[0] = v0.x; oth[1] = v0.y; oth[2]  = v0.z; oth[3]  = v0.w;
                    oth[4] = v1.x; oth[5] = v1.y; oth[6]  = v1.z; oth[7]  = v1.w;
                    oth[8] = v2.x; oth[9] = v2.y; oth[10] = v2.z; oth[11] = v2.w;
                } else {
                    oth[0] += v0.x; oth[1] += v0.y; oth[2]  += v0.z; oth[3]  += v0.w;
                    oth[4] += v1.x; oth[5] += v1.y; oth[6]  += v1.z; oth[7]  += v1.w;
                    oth[8] += v2.x; oth[9] += v2.y; oth[10] += v2.z; oth[11] += v2.w;
                }
            }
            #pragma unroll
            for (int xx = 0; xx < 11; ++xx) {
                float v = acc[xx] + oth[xx] + b;
                int pidx = (co * 13 + yy + 1) * PLSTRIDE + xx + 1;
                if (mode == 0) {
                    P1[pidx] = fmaxf(v, 0.f);
                } else if (mode == 1) {
                    float p = P0[pidx];
                    P0[pidx] = fmaxf(fmaf(0.1f, v, p), 0.f);
                } else {
                    int fo = co * 121 + yy * 11 + xx;
                    F[fo] = fmaxf(fmaf(0.1f, v, G2[fo]), 0.f);
                }
            }
        }
    };

    #pragma unroll
    for (int rb = 0; rb < 4; ++rb) {
        do_conv(P0, 2 * rb, 0);
        do_conv(P1, 2 * rb + 1, 1);
    }
    do_conv(P0, 8, 2);
    __syncthreads();

    if (t < 88) {
        int tco = t / 11, tyy = t - tco * 11;
        float s = 0.f;
        #pragma unroll
        for (int xx = 0; xx < 11; ++xx) s += F[tco * 121 + tyy * 11 + xx];
        rowsum[t] = s;
    }
    __syncthreads();
    if (t < 8) {
        float s = 0.f;
        #pragma unroll
        for (int j = 0; j < 11; ++j) s += rowsum[t * 11 + j];
        inv[t] = 1.f / s;
    }
    __syncthreads();
    for (int o = t; o < 968; o += 384)
        pa.out[n * 968 + o] = F[o] * inv[o / 121];
}

extern "C" void kernel_launch(void* const* d_in, const int* in_sizes, int n_in,
                              void* d_out, int out_size, void* d_ws, size_t ws_size,
                              hipStream_t stream) {
    const float* x = (const float*)d_in[0];
    const float* y = (const float*)d_in[1];
    const float* k = (const float*)d_in[2];
    const float* gamma = (const float*)d_in[4];

    const size_t xpad_fl = (size_t)64 * 256 * XPROW;
    const size_t e2_fl = (size_t)8 * 131072;
    const size_t need = (xpad_fl + e2_fl + 7744) * sizeof(float);

    float* G;
    if (ws_size >= need) {
        float* xpad = (float*)d_ws;
        float* E2 = xpad + xpad_fl;
        G = E2 + e2_fl;
        pad_kernel<<<256, 256, 0, stream>>>(x, xpad);
        blur_kernel<<<1024, 256, 0, stream>>>(xpad, y, k, E2);
        grad_kernel<<<704, 256, 0, stream>>>(xpad, E2, G);
    } else {
        float* E2 = (float*)d_ws;
        G = E2 + e2_fl;
        blur_kernel_ref<<<1024, 256, 0, stream>>>(x, y, k, E2);
        grad_kernel_ref<<<704, 256, 0, stream>>>(x, E2, G);
    }

    PArgs pa;
    for (int i = 0; i < 9; ++i) {
        pa.W[i] = (const float*)d_in[5 + 2 * i];
        pa.B[i] = (const float*)d_in[6 + 2 * i];
    }
    pa.k = k;
    pa.gamma = gamma;
    pa.G = G;
    pa.out = (float*)d_out;
    pronet_kernel<<<8, 384, 0, stream>>>(pa);
}